// Round 4
// baseline (278.838 us; speedup 1.0000x reference)
//
#include <hip/hip_runtime.h>
#include <hip/hip_bf16.h>
#include <hip/hip_fp16.h>
#include <math.h>

#define N_NODES 10000
#define N_EDGES 320000
#define IN_SIZE 256
#define H1 8
#define D1 64
#define F1 512
#define H2 1
#define D2 64
#define F2 64

// ---- simple LDS-tiled f32 GEMM: C[M,Ncols] = A[M,K] @ B[K,Ncols] ----
__global__ __launch_bounds__(256) void gemm_f32(const float* __restrict__ A,
                                                const float* __restrict__ B,
                                                float* __restrict__ C,
                                                int M, int Ncols, int K) {
  __shared__ float As[64][17];
  __shared__ float Bs[16][64];
  int tid = threadIdx.x;
  int tx = tid & 15, ty = tid >> 4;
  int rowBase = blockIdx.y * 64;
  int colBase = blockIdx.x * 64;
  int ar = tid >> 2;
  int ak = (tid & 3) << 2;
  int br = tid >> 4;
  int bc = (tid & 15) << 2;
  float acc[4][4] = {{0.f, 0.f, 0.f, 0.f}};
  for (int k0 = 0; k0 < K; k0 += 16) {
    float4 av = make_float4(0.f, 0.f, 0.f, 0.f);
    if (rowBase + ar < M)
      av = *reinterpret_cast<const float4*>(&A[(size_t)(rowBase + ar) * K + k0 + ak]);
    float4 bv = *reinterpret_cast<const float4*>(&B[(size_t)(k0 + br) * Ncols + colBase + bc]);
    __syncthreads();
    As[ar][ak + 0] = av.x; As[ar][ak + 1] = av.y;
    As[ar][ak + 2] = av.z; As[ar][ak + 3] = av.w;
    *reinterpret_cast<float4*>(&Bs[br][bc]) = bv;
    __syncthreads();
#pragma unroll
    for (int k = 0; k < 16; ++k) {
      float a0 = As[ty * 4 + 0][k], a1 = As[ty * 4 + 1][k];
      float a2 = As[ty * 4 + 2][k], a3 = As[ty * 4 + 3][k];
      float b0 = Bs[k][tx * 4 + 0], b1 = Bs[k][tx * 4 + 1];
      float b2 = Bs[k][tx * 4 + 2], b3 = Bs[k][tx * 4 + 3];
      acc[0][0] += a0 * b0; acc[0][1] += a0 * b1; acc[0][2] += a0 * b2; acc[0][3] += a0 * b3;
      acc[1][0] += a1 * b0; acc[1][1] += a1 * b1; acc[1][2] += a1 * b2; acc[1][3] += a1 * b3;
      acc[2][0] += a2 * b0; acc[2][1] += a2 * b1; acc[2][2] += a2 * b2; acc[2][3] += a2 * b3;
      acc[3][0] += a3 * b0; acc[3][1] += a3 * b1; acc[3][2] += a3 * b2; acc[3][3] += a3 * b3;
    }
  }
#pragma unroll
  for (int i = 0; i < 4; ++i) {
    int row = rowBase + ty * 4 + i;
    if (row < M) {
      float4 v = make_float4(acc[i][0], acc[i][1], acc[i][2], acc[i][3]);
      *reinterpret_cast<float4*>(&C[(size_t)row * Ncols + colBase + tx * 4]) = v;
    }
  }
}

// ---- f32 -> f16 payload copy ----
__global__ void f32_to_f16(const float* __restrict__ in, __half* __restrict__ out, int n4) {
  int i = blockIdx.x * blockDim.x + threadIdx.x;
  if (i < n4) {
    float4 v = reinterpret_cast<const float4*>(in)[i];
    __half2 a = __floats2half2_rn(v.x, v.y);
    __half2 b = __floats2half2_rn(v.z, v.w);
    reinterpret_cast<__half2*>(out)[i * 2 + 0] = a;
    reinterpret_cast<__half2*>(out)[i * 2 + 1] = b;
  }
}

// ---- per-node attention projections el/er ----
__global__ void el_er_kernel(const float* __restrict__ ft, const float* __restrict__ al,
                             const float* __restrict__ ar, float* __restrict__ el,
                             float* __restrict__ er, int H) {
  int n = blockIdx.x;
  int t = threadIdx.x;
  float v = ft[(size_t)n * H * 64 + t];
  float pl = v * al[t];
  float pr = v * ar[t];
#pragma unroll
  for (int off = 32; off > 0; off >>= 1) {
    pl += __shfl_down(pl, off);
    pr += __shfl_down(pr, off);
  }
  if ((t & 63) == 0) {
    int h = t >> 6;
    el[n * H + h] = pl;
    er[n * H + h] = pr;
  }
}

// ---- CSR build ----
__global__ void hist_kernel(const int* __restrict__ dst, int* __restrict__ counts, int E) {
  int e = blockIdx.x * blockDim.x + threadIdx.x;
  if (e < E) atomicAdd(&counts[dst[e]], 1);
}

__global__ __launch_bounds__(1024) void scan_kernel(const int* __restrict__ counts,
                                                    int* __restrict__ row_off,
                                                    int* __restrict__ cursor, int N) {
  __shared__ int part[1024];
  int tid = threadIdx.x;
  int T = blockDim.x;
  int chunk = (N + T - 1) / T;
  int beg = tid * chunk;
  int end = min(beg + chunk, N);
  int s = 0;
  for (int i = beg; i < end; ++i) s += counts[i];
  part[tid] = s;
  __syncthreads();
  for (int off = 1; off < T; off <<= 1) {
    int v = (tid >= off) ? part[tid - off] : 0;
    __syncthreads();
    part[tid] += v;
    __syncthreads();
  }
  int run = (tid > 0) ? part[tid - 1] : 0;
  for (int i = beg; i < end; ++i) {
    row_off[i] = run;
    cursor[i] = run;
    run += counts[i];
  }
  if (tid == T - 1) row_off[N] = run;
}

__global__ void scatter_kernel(const int* __restrict__ src, const int* __restrict__ dst,
                               int* __restrict__ cursor, int* __restrict__ src_csr, int E) {
  int e = blockIdx.x * blockDim.x + threadIdx.x;
  if (e < E) {
    int p = atomicAdd(&cursor[dst[e]], 1);
    src_csr[p] = src[e];
  }
}

// ---- SGPR broadcast helpers (literal lane index -> v_readlane) ----
__device__ __forceinline__ int bcast_i(int v, int l) {
  return __builtin_amdgcn_readlane(v, l);
}
__device__ __forceinline__ float bcast_f(float v, int l) {
  return __int_as_float(__builtin_amdgcn_readlane(__float_as_int(v), l));
}

// ---- fused per-node GAT with SPLIT waves per (node,head) + LDS merge ----
// Wave layout: w -> (node ni, head h, split sw). Each wave runs online softmax
// + aggregation over its edge slice; partials merged via LDS. Inner loop uses
// fully-unrolled literal-lane readlane broadcasts (no ds_bpermute) and fp16
// feature gather.
template <int H, int SPLIT, int NPB, int DO_ELU>
__global__ __launch_bounds__(NPB* H* SPLIT * 64) void gat_node_kernel(
    const int* __restrict__ row_off, const int* __restrict__ src_csr,
    const float* __restrict__ el, const float* __restrict__ er,
    const __half* __restrict__ fth, const float* __restrict__ bias,
    float* __restrict__ out, int N) {
  constexpr int F = H * 64;
  constexpr int NW = NPB * H * SPLIT;
  __shared__ float lds_acc[NW][64];
  __shared__ float lds_ms[NW][2];
  int t = threadIdx.x;
  int w = t >> 6;
  int lane = t & 63;
  int ni = w / (H * SPLIT);
  int rem = w % (H * SPLIT);
  int h = rem / SPLIT;
  int sw = rem % SPLIT;
  int n = blockIdx.x * NPB + ni;  // grids sized exactly
  int beg = row_off[n], end = row_off[n + 1];
  int deg = end - beg;
  int per = (deg + SPLIT - 1) / SPLIT;
  int b2 = beg + sw * per; if (b2 > end) b2 = end;
  int e2 = b2 + per;       if (e2 > end) e2 = end;
  float er_h = er[n * H + h];
  float m_run = -INFINITY, s_run = 0.f, acc = 0.f;
  int off = h * 64 + lane;
  for (int c = b2; c < e2; c += 64) {
    int cnt = e2 - c; if (cnt > 64) cnt = 64;
    int s_reg = 0;
    float lg = -INFINITY;
    if (lane < cnt) {
      s_reg = src_csr[c + lane];
      float xv = el[s_reg * H + h] + er_h;
      lg = (xv >= 0.f) ? xv : 0.2f * xv;
    }
    float m_c = lg;
#pragma unroll
    for (int o = 32; o > 0; o >>= 1) m_c = fmaxf(m_c, __shfl_xor(m_c, o));
    float m_new = fmaxf(m_run, m_c);
    float ex = (lane < cnt) ? __expf(lg - m_new) : 0.f;
    float sum_c = ex;
#pragma unroll
    for (int o = 32; o > 0; o >>= 1) sum_c += __shfl_xor(sum_c, o);
    float scale = (m_run == -INFINITY) ? 0.f : __expf(m_run - m_new);
    acc *= scale;
    s_run = s_run * scale + sum_c;
    m_run = m_new;
#pragma unroll
    for (int g = 0; g < 8; ++g) {
      if (g * 8 < cnt) {
        int sg[8];
        float eg[8], f[8];
#pragma unroll
        for (int j = 0; j < 8; ++j) {
          sg[j] = bcast_i(s_reg, g * 8 + j);
          eg[j] = bcast_f(ex, g * 8 + j);
        }
#pragma unroll
        for (int j = 0; j < 8; ++j)
          f[j] = __half2float(fth[(size_t)sg[j] * F + off]);
#pragma unroll
        for (int j = 0; j < 8; ++j) acc += eg[j] * f[j];
      }
    }
  }
  if (SPLIT > 1) {
    lds_acc[w][lane] = acc;
    if (lane == 0) { lds_ms[w][0] = m_run; lds_ms[w][1] = s_run; }
    __syncthreads();
    if (sw != 0) return;
    float m_star = m_run;
#pragma unroll
    for (int k = 1; k < SPLIT; ++k) m_star = fmaxf(m_star, lds_ms[w + k][0]);
    float stot = 0.f, atot = 0.f;
#pragma unroll
    for (int k = 0; k < SPLIT; ++k) {
      float mk = lds_ms[w + k][0];
      float sc = (mk == -INFINITY) ? 0.f : __expf(mk - m_star);
      stot += lds_ms[w + k][1] * sc;
      atot += lds_acc[w + k][lane] * sc;
    }
    s_run = stot;
    acc = atot;
  }
  float inv = (s_run > 0.f) ? (1.f / s_run) : 0.f;
  float o = acc * inv + bias[off];
  if (DO_ELU) o = (o > 0.f) ? o : (__expf(o) - 1.f);
  out[(size_t)n * F + off] = o;
}

extern "C" void kernel_launch(void* const* d_in, const int* in_sizes, int n_in,
                              void* d_out, int out_size, void* d_ws, size_t ws_size,
                              hipStream_t stream) {
  const float* x   = (const float*)d_in[0];
  const int*   src = (const int*)d_in[1];
  const int*   dst = (const int*)d_in[2];
  const float* W1  = (const float*)d_in[3];
  const float* al1 = (const float*)d_in[4];
  const float* ar1 = (const float*)d_in[5];
  const float* b1  = (const float*)d_in[6];
  const float* W2  = (const float*)d_in[7];
  const float* al2 = (const float*)d_in[8];
  const float* ar2 = (const float*)d_in[9];
  const float* b2  = (const float*)d_in[10];
  float* out = (float*)d_out;

  char* ws = (char*)d_ws;
  size_t off = 0;
  auto alloc = [&](size_t bytes) -> void* {
    void* p = ws + off;
    off += (bytes + 255) & ~(size_t)255;
    return p;
  };
  size_t zbeg = off;
  int* counts = (int*)alloc((size_t)N_NODES * 4);
  size_t zend = off;
  float*  ft1  = (float*)alloc((size_t)N_NODES * F1 * 4);
  float*  h1   = (float*)alloc((size_t)N_NODES * F1 * 4);
  float*  ft2  = (float*)alloc((size_t)N_NODES * F2 * 4);
  __half* ft1h = (__half*)alloc((size_t)N_NODES * F1 * 2);
  __half* ft2h = (__half*)alloc((size_t)N_NODES * F2 * 2);
  float* el1 = (float*)alloc((size_t)N_NODES * H1 * 4);
  float* er1 = (float*)alloc((size_t)N_NODES * H1 * 4);
  float* el2 = (float*)alloc((size_t)N_NODES * 4);
  float* er2 = (float*)alloc((size_t)N_NODES * 4);
  int* row_off = (int*)alloc((size_t)(N_NODES + 1) * 4);
  int* cursor  = (int*)alloc((size_t)N_NODES * 4);
  int* src_csr = (int*)alloc((size_t)N_EDGES * 4);
  (void)ws_size; (void)in_sizes; (void)n_in; (void)out_size;

  hipMemsetAsync(ws + zbeg, 0, zend - zbeg, stream);

  dim3 b256(256);
  int egrid = (N_EDGES + 255) / 256;

  // CSR build
  hist_kernel<<<egrid, b256, 0, stream>>>(dst, counts, N_EDGES);
  scan_kernel<<<1, 1024, 0, stream>>>(counts, row_off, cursor, N_NODES);
  scatter_kernel<<<egrid, b256, 0, stream>>>(src, dst, cursor, src_csr, N_EDGES);

  // ---- layer 1 ----
  gemm_f32<<<dim3(F1 / 64, (N_NODES + 63) / 64), b256, 0, stream>>>(x, W1, ft1, N_NODES, F1, IN_SIZE);
  f32_to_f16<<<(N_NODES * F1 / 4 + 255) / 256, b256, 0, stream>>>(ft1, ft1h, N_NODES * F1 / 4);
  el_er_kernel<<<N_NODES, H1 * 64, 0, stream>>>(ft1, al1, ar1, el1, er1, H1);
  gat_node_kernel<H1, 2, 1, 1><<<N_NODES, H1 * 2 * 64, 0, stream>>>(
      row_off, src_csr, el1, er1, ft1h, b1, h1, N_NODES);

  // ---- layer 2 ----
  gemm_f32<<<dim3(F2 / 64, (N_NODES + 63) / 64), b256, 0, stream>>>(h1, W2, ft2, N_NODES, F2, F1);
  f32_to_f16<<<(N_NODES * F2 / 4 + 255) / 256, b256, 0, stream>>>(ft2, ft2h, N_NODES * F2 / 4);
  el_er_kernel<<<N_NODES, 64, 0, stream>>>(ft2, al2, ar2, el2, er2, H2);
  gat_node_kernel<H2, 4, 4, 0><<<N_NODES / 4, 4 * H2 * 4 * 64, 0, stream>>>(
      row_off, src_csr, el2, er2, ft2h, b2, out, N_NODES);
}

// Round 5
// 217.779 us; speedup vs baseline: 1.2804x; 1.2804x over previous
//
#include <hip/hip_runtime.h>
#include <hip/hip_bf16.h>
#include <hip/hip_fp16.h>
#include <math.h>

#define N_NODES 10000
#define N_EDGES 320000
#define IN_SIZE 256
#define H1 8
#define D1 64
#define F1 512
#define H2 1
#define D2 64
#define F2 64

// ---- LDS-tiled f32 GEMM fused epilogue: writes f16 C, computes el/er ----
// col tile (64) == head width, so each block owns complete head columns and
// can reduce el/er = C . al/ar per row with a 16-lane shfl tree.
__global__ __launch_bounds__(256) void gemm_epi(const float* __restrict__ A,
                                                const float* __restrict__ B,
                                                __half* __restrict__ Ch,
                                                const float* __restrict__ al,
                                                const float* __restrict__ ar,
                                                float* __restrict__ el,
                                                float* __restrict__ er,
                                                int M, int Ncols, int K, int H) {
  __shared__ float As[64][17];
  __shared__ float Bs[16][64];
  int tid = threadIdx.x;
  int tx = tid & 15, ty = tid >> 4;
  int rowBase = blockIdx.y * 64;
  int colBase = blockIdx.x * 64;
  int ar_ = tid >> 2;
  int ak = (tid & 3) << 2;
  int br = tid >> 4;
  int bc = (tid & 15) << 2;
  float acc[4][4] = {{0.f, 0.f, 0.f, 0.f}};
  for (int k0 = 0; k0 < K; k0 += 16) {
    float4 av = make_float4(0.f, 0.f, 0.f, 0.f);
    if (rowBase + ar_ < M)
      av = *reinterpret_cast<const float4*>(&A[(size_t)(rowBase + ar_) * K + k0 + ak]);
    float4 bv = *reinterpret_cast<const float4*>(&B[(size_t)(k0 + br) * Ncols + colBase + bc]);
    __syncthreads();
    As[ar_][ak + 0] = av.x; As[ar_][ak + 1] = av.y;
    As[ar_][ak + 2] = av.z; As[ar_][ak + 3] = av.w;
    *reinterpret_cast<float4*>(&Bs[br][bc]) = bv;
    __syncthreads();
#pragma unroll
    for (int k = 0; k < 16; ++k) {
      float a0 = As[ty * 4 + 0][k], a1 = As[ty * 4 + 1][k];
      float a2 = As[ty * 4 + 2][k], a3 = As[ty * 4 + 3][k];
      float b0 = Bs[k][tx * 4 + 0], b1 = Bs[k][tx * 4 + 1];
      float b2 = Bs[k][tx * 4 + 2], b3 = Bs[k][tx * 4 + 3];
      acc[0][0] += a0 * b0; acc[0][1] += a0 * b1; acc[0][2] += a0 * b2; acc[0][3] += a0 * b3;
      acc[1][0] += a1 * b0; acc[1][1] += a1 * b1; acc[1][2] += a1 * b2; acc[1][3] += a1 * b3;
      acc[2][0] += a2 * b0; acc[2][1] += a2 * b1; acc[2][2] += a2 * b2; acc[2][3] += a2 * b3;
      acc[3][0] += a3 * b0; acc[3][1] += a3 * b1; acc[3][2] += a3 * b2; acc[3][3] += a3 * b3;
    }
  }
  int h = colBase >> 6;
  float alv[4], arv[4];
#pragma unroll
  for (int j = 0; j < 4; ++j) {
    alv[j] = al[colBase + tx * 4 + j];
    arv[j] = ar[colBase + tx * 4 + j];
  }
#pragma unroll
  for (int i = 0; i < 4; ++i) {
    int row = rowBase + ty * 4 + i;
    bool ok = row < M;
    if (ok) {
      __half2 p0 = __floats2half2_rn(acc[i][0], acc[i][1]);
      __half2 p1 = __floats2half2_rn(acc[i][2], acc[i][3]);
      __half2* cp = reinterpret_cast<__half2*>(&Ch[(size_t)row * Ncols + colBase + tx * 4]);
      cp[0] = p0; cp[1] = p1;
    }
    float pl = acc[i][0] * alv[0] + acc[i][1] * alv[1] + acc[i][2] * alv[2] + acc[i][3] * alv[3];
    float pr = acc[i][0] * arv[0] + acc[i][1] * arv[1] + acc[i][2] * arv[2] + acc[i][3] * arv[3];
#pragma unroll
    for (int o = 8; o > 0; o >>= 1) {
      pl += __shfl_xor(pl, o);
      pr += __shfl_xor(pr, o);
    }
    if (tx == 0 && ok) {
      el[(size_t)row * H + h] = pl;
      er[(size_t)row * H + h] = pr;
    }
  }
}

// ---- CSR build ----
__global__ void hist_kernel(const int* __restrict__ dst, int* __restrict__ counts, int E) {
  int e = blockIdx.x * blockDim.x + threadIdx.x;
  if (e < E) atomicAdd(&counts[dst[e]], 1);
}

__global__ __launch_bounds__(1024) void scan_kernel(const int* __restrict__ counts,
                                                    int* __restrict__ row_off,
                                                    int* __restrict__ cursor, int N) {
  __shared__ int part[1024];
  int tid = threadIdx.x;
  int T = blockDim.x;
  int chunk = (N + T - 1) / T;
  int beg = tid * chunk;
  int end = min(beg + chunk, N);
  int s = 0;
  for (int i = beg; i < end; ++i) s += counts[i];
  part[tid] = s;
  __syncthreads();
  for (int off = 1; off < T; off <<= 1) {
    int v = (tid >= off) ? part[tid - off] : 0;
    __syncthreads();
    part[tid] += v;
    __syncthreads();
  }
  int run = (tid > 0) ? part[tid - 1] : 0;
  for (int i = beg; i < end; ++i) {
    row_off[i] = run;
    cursor[i] = run;
    run += counts[i];
  }
  if (tid == T - 1) row_off[N] = run;
}

__global__ void scatter_kernel(const int* __restrict__ src, const int* __restrict__ dst,
                               int* __restrict__ cursor, int* __restrict__ src_csr, int E) {
  int e = blockIdx.x * blockDim.x + threadIdx.x;
  if (e < E) {
    int p = atomicAdd(&cursor[dst[e]], 1);
    src_csr[p] = src[e];
  }
}

__device__ __forceinline__ int bcast_i(int v, int l) {
  return __builtin_amdgcn_readlane(v, l);
}
__device__ __forceinline__ float bcast_f(float v, int l) {
  return __int_as_float(__builtin_amdgcn_readlane(__float_as_int(v), l));
}

// ---- fused GAT, 2 heads per wave, half2 gather ----
// lane = 32*hi + j: hi = head within pair, j = channel-pair (ch 2j,2j+1).
// Per 32-edge chunk: half-wave online softmax; gather broadcasts src via one
// readlane, ex via two readlanes + cndmask; one dword (half2) load per lane.
template <int H, int SPLIT, int DO_ELU>
__global__ __launch_bounds__((H / 2) * SPLIT * 64) void gat_pair_kernel(
    const int* __restrict__ row_off, const int* __restrict__ src_csr,
    const float* __restrict__ el, const float* __restrict__ er,
    const __half* __restrict__ fth, const float* __restrict__ bias,
    float* __restrict__ out, int N) {
  constexpr int F = H * 64;
  constexpr int NW = (H / 2) * SPLIT;
  __shared__ float lds_acc[NW][64][2];
  __shared__ float lds_ms[NW][2][2];
  int t = threadIdx.x;
  int w = t >> 6;
  int lane = t & 63;
  int hp = w / SPLIT;
  int sw = w % SPLIT;
  int hi = lane >> 5;
  int j = lane & 31;
  int h = hp * 2 + hi;
  int n = blockIdx.x;
  int beg = row_off[n], end = row_off[n + 1];
  int deg = end - beg;
  int per = (deg + SPLIT - 1) / SPLIT;
  int b2 = beg + sw * per; if (b2 > end) b2 = end;
  int e2 = b2 + per;       if (e2 > end) e2 = end;
  float er_h = er[n * H + h];
  float m_run = -INFINITY, s_run = 0.f, acc0 = 0.f, acc1 = 0.f;
  int choff = h * 32 + j;  // half2 index within a row
  for (int c = b2; c < e2; c += 32) {
    int cnt = e2 - c; if (cnt > 32) cnt = 32;
    int s_reg = 0;
    float lg = -INFINITY;
    if (j < cnt) {
      s_reg = src_csr[c + j];
      float xv = el[s_reg * H + h] + er_h;
      lg = (xv >= 0.f) ? xv : 0.2f * xv;
    }
    float m_c = lg;
#pragma unroll
    for (int o = 16; o > 0; o >>= 1) m_c = fmaxf(m_c, __shfl_xor(m_c, o));
    float m_new = fmaxf(m_run, m_c);
    float ex = (j < cnt) ? __expf(lg - m_new) : 0.f;
    float sum_c = ex;
#pragma unroll
    for (int o = 16; o > 0; o >>= 1) sum_c += __shfl_xor(sum_c, o);
    float scale = (m_run == -INFINITY) ? 0.f : __expf(m_run - m_new);
    acc0 *= scale; acc1 *= scale;
    s_run = s_run * scale + sum_c;
    m_run = m_new;
#pragma unroll
    for (int g = 0; g < 4; ++g) {
      if (g * 8 < cnt) {
#pragma unroll
        for (int jj = 0; jj < 8; ++jj) {
          const int idx = g * 8 + jj;
          int s0 = bcast_i(s_reg, idx);
          float e0 = bcast_f(ex, idx);
          float e1 = bcast_f(ex, 32 + idx);
          float e = hi ? e1 : e0;
          const __half2* p = reinterpret_cast<const __half2*>(fth + (size_t)s0 * F);
          float2 f = __half22float2(p[choff]);
          acc0 += e * f.x;
          acc1 += e * f.y;
        }
      }
    }
  }
  if (SPLIT > 1) {
    lds_acc[w][lane][0] = acc0;
    lds_acc[w][lane][1] = acc1;
    if (j == 0) { lds_ms[w][hi][0] = m_run; lds_ms[w][hi][1] = s_run; }
    __syncthreads();
    if (sw != 0) return;
    float m_star = m_run;
#pragma unroll
    for (int k = 1; k < SPLIT; ++k) m_star = fmaxf(m_star, lds_ms[w + k][hi][0]);
    float sc0 = (m_run == -INFINITY) ? 0.f : __expf(m_run - m_star);
    acc0 *= sc0; acc1 *= sc0;
    s_run *= sc0;
#pragma unroll
    for (int k = 1; k < SPLIT; ++k) {
      float mk = lds_ms[w + k][hi][0];
      float sc = (mk == -INFINITY) ? 0.f : __expf(mk - m_star);
      s_run += lds_ms[w + k][hi][1] * sc;
      acc0 += lds_acc[w + k][lane][0] * sc;
      acc1 += lds_acc[w + k][lane][1] * sc;
    }
  }
  float inv = (s_run > 0.f) ? (1.f / s_run) : 0.f;
  float o0 = acc0 * inv + bias[h * 64 + j * 2 + 0];
  float o1 = acc1 * inv + bias[h * 64 + j * 2 + 1];
  if (DO_ELU) {
    o0 = (o0 > 0.f) ? o0 : (__expf(o0) - 1.f);
    o1 = (o1 > 0.f) ? o1 : (__expf(o1) - 1.f);
  }
  *reinterpret_cast<float2*>(&out[(size_t)n * F + h * 64 + j * 2]) = make_float2(o0, o1);
}

// ---- scalar-gather GAT kept for layer 2 (tiny L2-resident table) ----
template <int H, int SPLIT, int NPB, int DO_ELU>
__global__ __launch_bounds__(NPB* H* SPLIT * 64) void gat_node_kernel(
    const int* __restrict__ row_off, const int* __restrict__ src_csr,
    const float* __restrict__ el, const float* __restrict__ er,
    const __half* __restrict__ fth, const float* __restrict__ bias,
    float* __restrict__ out, int N) {
  constexpr int F = H * 64;
  constexpr int NW = NPB * H * SPLIT;
  __shared__ float lds_acc[NW][64];
  __shared__ float lds_ms[NW][2];
  int t = threadIdx.x;
  int w = t >> 6;
  int lane = t & 63;
  int ni = w / (H * SPLIT);
  int rem = w % (H * SPLIT);
  int h = rem / SPLIT;
  int sw = rem % SPLIT;
  int n = blockIdx.x * NPB + ni;
  int beg = row_off[n], end = row_off[n + 1];
  int deg = end - beg;
  int per = (deg + SPLIT - 1) / SPLIT;
  int b2 = beg + sw * per; if (b2 > end) b2 = end;
  int e2 = b2 + per;       if (e2 > end) e2 = end;
  float er_h = er[n * H + h];
  float m_run = -INFINITY, s_run = 0.f, acc = 0.f;
  int off = h * 64 + lane;
  for (int c = b2; c < e2; c += 64) {
    int cnt = e2 - c; if (cnt > 64) cnt = 64;
    int s_reg = 0;
    float lg = -INFINITY;
    if (lane < cnt) {
      s_reg = src_csr[c + lane];
      float xv = el[s_reg * H + h] + er_h;
      lg = (xv >= 0.f) ? xv : 0.2f * xv;
    }
    float m_c = lg;
#pragma unroll
    for (int o = 32; o > 0; o >>= 1) m_c = fmaxf(m_c, __shfl_xor(m_c, o));
    float m_new = fmaxf(m_run, m_c);
    float ex = (lane < cnt) ? __expf(lg - m_new) : 0.f;
    float sum_c = ex;
#pragma unroll
    for (int o = 32; o > 0; o >>= 1) sum_c += __shfl_xor(sum_c, o);
    float scale = (m_run == -INFINITY) ? 0.f : __expf(m_run - m_new);
    acc *= scale;
    s_run = s_run * scale + sum_c;
    m_run = m_new;
#pragma unroll
    for (int g = 0; g < 8; ++g) {
      if (g * 8 < cnt) {
        int sg[8];
        float eg[8], f[8];
#pragma unroll
        for (int jj = 0; jj < 8; ++jj) {
          sg[jj] = bcast_i(s_reg, g * 8 + jj);
          eg[jj] = bcast_f(ex, g * 8 + jj);
        }
#pragma unroll
        for (int jj = 0; jj < 8; ++jj)
          f[jj] = __half2float(fth[(size_t)sg[jj] * F + off]);
#pragma unroll
        for (int jj = 0; jj < 8; ++jj) acc += eg[jj] * f[jj];
      }
    }
  }
  if (SPLIT > 1) {
    lds_acc[w][lane] = acc;
    if (lane == 0) { lds_ms[w][0] = m_run; lds_ms[w][1] = s_run; }
    __syncthreads();
    if (sw != 0) return;
    float m_star = m_run;
#pragma unroll
    for (int k = 1; k < SPLIT; ++k) m_star = fmaxf(m_star, lds_ms[w + k][0]);
    float stot = 0.f, atot = 0.f;
#pragma unroll
    for (int k = 0; k < SPLIT; ++k) {
      float mk = lds_ms[w + k][0];
      float sc = (mk == -INFINITY) ? 0.f : __expf(mk - m_star);
      stot += lds_ms[w + k][1] * sc;
      atot += lds_acc[w + k][lane] * sc;
    }
    s_run = stot;
    acc = atot;
  }
  float inv = (s_run > 0.f) ? (1.f / s_run) : 0.f;
  float o = acc * inv + bias[off];
  if (DO_ELU) o = (o > 0.f) ? o : (__expf(o) - 1.f);
  out[(size_t)n * F + off] = o;
}

extern "C" void kernel_launch(void* const* d_in, const int* in_sizes, int n_in,
                              void* d_out, int out_size, void* d_ws, size_t ws_size,
                              hipStream_t stream) {
  const float* x   = (const float*)d_in[0];
  const int*   src = (const int*)d_in[1];
  const int*   dst = (const int*)d_in[2];
  const float* W1  = (const float*)d_in[3];
  const float* al1 = (const float*)d_in[4];
  const float* ar1 = (const float*)d_in[5];
  const float* b1  = (const float*)d_in[6];
  const float* W2  = (const float*)d_in[7];
  const float* al2 = (const float*)d_in[8];
  const float* ar2 = (const float*)d_in[9];
  const float* b2  = (const float*)d_in[10];
  float* out = (float*)d_out;

  char* ws = (char*)d_ws;
  size_t off = 0;
  auto alloc = [&](size_t bytes) -> void* {
    void* p = ws + off;
    off += (bytes + 255) & ~(size_t)255;
    return p;
  };
  size_t zbeg = off;
  int* counts = (int*)alloc((size_t)N_NODES * 4);
  size_t zend = off;
  float*  h1   = (float*)alloc((size_t)N_NODES * F1 * 4);
  __half* ft1h = (__half*)alloc((size_t)N_NODES * F1 * 2);
  __half* ft2h = (__half*)alloc((size_t)N_NODES * F2 * 2);
  float* el1 = (float*)alloc((size_t)N_NODES * H1 * 4);
  float* er1 = (float*)alloc((size_t)N_NODES * H1 * 4);
  float* el2 = (float*)alloc((size_t)N_NODES * 4);
  float* er2 = (float*)alloc((size_t)N_NODES * 4);
  int* row_off = (int*)alloc((size_t)(N_NODES + 1) * 4);
  int* cursor  = (int*)alloc((size_t)N_NODES * 4);
  int* src_csr = (int*)alloc((size_t)N_EDGES * 4);
  (void)ws_size; (void)in_sizes; (void)n_in; (void)out_size;

  hipMemsetAsync(ws + zbeg, 0, zend - zbeg, stream);

  dim3 b256(256);
  int egrid = (N_EDGES + 255) / 256;

  // CSR build
  hist_kernel<<<egrid, b256, 0, stream>>>(dst, counts, N_EDGES);
  scan_kernel<<<1, 1024, 0, stream>>>(counts, row_off, cursor, N_NODES);
  scatter_kernel<<<egrid, b256, 0, stream>>>(src, dst, cursor, src_csr, N_EDGES);

  // ---- layer 1: GEMM (+f16 copy, el/er epilogue) then fused GAT ----
  gemm_epi<<<dim3(F1 / 64, (N_NODES + 63) / 64), b256, 0, stream>>>(
      x, W1, ft1h, al1, ar1, el1, er1, N_NODES, F1, IN_SIZE, H1);
  gat_pair_kernel<H1, 2, 1><<<N_NODES, (H1 / 2) * 2 * 64, 0, stream>>>(
      row_off, src_csr, el1, er1, ft1h, b1, h1, N_NODES);

  // ---- layer 2 ----
  gemm_epi<<<dim3(F2 / 64, (N_NODES + 63) / 64), b256, 0, stream>>>(
      h1, W2, ft2h, al2, ar2, el2, er2, N_NODES, F2, F1, H2);
  gat_node_kernel<H2, 4, 4, 0><<<N_NODES / 4, 4 * H2 * 4 * 64, 0, stream>>>(
      row_off, src_csr, el2, er2, ft2h, b2, out, N_NODES);
}

// Round 6
// 216.399 us; speedup vs baseline: 1.2885x; 1.0064x over previous
//
#include <hip/hip_runtime.h>
#include <hip/hip_bf16.h>
#include <hip/hip_fp16.h>
#include <math.h>

#define N_NODES 10000
#define N_EDGES 320000
#define IN_SIZE 256
#define H1 8
#define D1 64
#define F1 512
#define H2 1
#define D2 64
#define F2 64

// ---- LDS-tiled f32 GEMM fused epilogue: writes f16 C, computes el/er ----
__global__ __launch_bounds__(256) void gemm_epi(const float* __restrict__ A,
                                                const float* __restrict__ B,
                                                __half* __restrict__ Ch,
                                                const float* __restrict__ al,
                                                const float* __restrict__ ar,
                                                float* __restrict__ el,
                                                float* __restrict__ er,
                                                int M, int Ncols, int K, int H) {
  __shared__ float As[64][17];
  __shared__ float Bs[16][64];
  int tid = threadIdx.x;
  int tx = tid & 15, ty = tid >> 4;
  int rowBase = blockIdx.y * 64;
  int colBase = blockIdx.x * 64;
  int ar_ = tid >> 2;
  int ak = (tid & 3) << 2;
  int br = tid >> 4;
  int bc = (tid & 15) << 2;
  float acc[4][4] = {{0.f, 0.f, 0.f, 0.f}};
  for (int k0 = 0; k0 < K; k0 += 16) {
    float4 av = make_float4(0.f, 0.f, 0.f, 0.f);
    if (rowBase + ar_ < M)
      av = *reinterpret_cast<const float4*>(&A[(size_t)(rowBase + ar_) * K + k0 + ak]);
    float4 bv = *reinterpret_cast<const float4*>(&B[(size_t)(k0 + br) * Ncols + colBase + bc]);
    __syncthreads();
    As[ar_][ak + 0] = av.x; As[ar_][ak + 1] = av.y;
    As[ar_][ak + 2] = av.z; As[ar_][ak + 3] = av.w;
    *reinterpret_cast<float4*>(&Bs[br][bc]) = bv;
    __syncthreads();
#pragma unroll
    for (int k = 0; k < 16; ++k) {
      float a0 = As[ty * 4 + 0][k], a1 = As[ty * 4 + 1][k];
      float a2 = As[ty * 4 + 2][k], a3 = As[ty * 4 + 3][k];
      float b0 = Bs[k][tx * 4 + 0], b1 = Bs[k][tx * 4 + 1];
      float b2 = Bs[k][tx * 4 + 2], b3 = Bs[k][tx * 4 + 3];
      acc[0][0] += a0 * b0; acc[0][1] += a0 * b1; acc[0][2] += a0 * b2; acc[0][3] += a0 * b3;
      acc[1][0] += a1 * b0; acc[1][1] += a1 * b1; acc[1][2] += a1 * b2; acc[1][3] += a1 * b3;
      acc[2][0] += a2 * b0; acc[2][1] += a2 * b1; acc[2][2] += a2 * b2; acc[2][3] += a2 * b3;
      acc[3][0] += a3 * b0; acc[3][1] += a3 * b1; acc[3][2] += a3 * b2; acc[3][3] += a3 * b3;
    }
  }
  int h = colBase >> 6;
  float alv[4], arv[4];
#pragma unroll
  for (int j = 0; j < 4; ++j) {
    alv[j] = al[colBase + tx * 4 + j];
    arv[j] = ar[colBase + tx * 4 + j];
  }
#pragma unroll
  for (int i = 0; i < 4; ++i) {
    int row = rowBase + ty * 4 + i;
    bool ok = row < M;
    if (ok) {
      __half2 p0 = __floats2half2_rn(acc[i][0], acc[i][1]);
      __half2 p1 = __floats2half2_rn(acc[i][2], acc[i][3]);
      __half2* cp = reinterpret_cast<__half2*>(&Ch[(size_t)row * Ncols + colBase + tx * 4]);
      cp[0] = p0; cp[1] = p1;
    }
    float pl = acc[i][0] * alv[0] + acc[i][1] * alv[1] + acc[i][2] * alv[2] + acc[i][3] * alv[3];
    float pr = acc[i][0] * arv[0] + acc[i][1] * arv[1] + acc[i][2] * arv[2] + acc[i][3] * arv[3];
#pragma unroll
    for (int o = 8; o > 0; o >>= 1) {
      pl += __shfl_xor(pl, o);
      pr += __shfl_xor(pr, o);
    }
    if (tx == 0 && ok) {
      el[(size_t)row * H + h] = pl;
      er[(size_t)row * H + h] = pr;
    }
  }
}

// ---- CSR build ----
__global__ void hist_kernel(const int* __restrict__ dst, int* __restrict__ counts, int E) {
  int e = blockIdx.x * blockDim.x + threadIdx.x;
  if (e < E) atomicAdd(&counts[dst[e]], 1);
}

__global__ __launch_bounds__(1024) void scan_kernel(const int* __restrict__ counts,
                                                    int* __restrict__ row_off,
                                                    int* __restrict__ cursor, int N) {
  __shared__ int part[1024];
  int tid = threadIdx.x;
  int T = blockDim.x;
  int chunk = (N + T - 1) / T;
  int beg = tid * chunk;
  int end = min(beg + chunk, N);
  int s = 0;
  for (int i = beg; i < end; ++i) s += counts[i];
  part[tid] = s;
  __syncthreads();
  for (int off = 1; off < T; off <<= 1) {
    int v = (tid >= off) ? part[tid - off] : 0;
    __syncthreads();
    part[tid] += v;
    __syncthreads();
  }
  int run = (tid > 0) ? part[tid - 1] : 0;
  for (int i = beg; i < end; ++i) {
    row_off[i] = run;
    cursor[i] = run;
    run += counts[i];
  }
  if (tid == T - 1) row_off[N] = run;
}

__global__ void scatter_kernel(const int* __restrict__ src, const int* __restrict__ dst,
                               int* __restrict__ cursor, int* __restrict__ src_csr, int E) {
  int e = blockIdx.x * blockDim.x + threadIdx.x;
  if (e < E) {
    int p = atomicAdd(&cursor[dst[e]], 1);
    src_csr[p] = src[e];
  }
}

__device__ __forceinline__ int bcast_i(int v, int l) {
  return __builtin_amdgcn_readlane(v, l);
}

// ---- fused GAT layer 1: one wave per node, ALL 8 heads per wave ----
// Chunk of 8 edges per iteration.
//   logit phase:  lane = e*8 + h  (e=lane>>3 edge slot, h=lane&7 head)
//   agg phase:    lane = (head, quad) : head = lane&7, quad = lane>>3,
//                 channels = head*64 + quad*8 .. +7, dwordx4 f16 gather
// ex broadcast per edge via one ds_bpermute; loads batched (MLP=8).
template <int NPB>
__global__ __launch_bounds__(NPB * 64) void gat_l1_kernel(
    const int* __restrict__ row_off, const int* __restrict__ src_csr,
    const float* __restrict__ el, const float* __restrict__ er,
    const __half* __restrict__ fth, const float* __restrict__ bias,
    float* __restrict__ out, int N) {
  int t = threadIdx.x;
  int w = t >> 6, lane = t & 63;
  int n = blockIdx.x * NPB + w;
  int e = lane >> 3;
  int hl = lane & 7;
  int ch = (lane & 7) * 64 + (lane >> 3) * 8;   // agg-phase channel base
  int bpbase = (lane & 7) * 4;                  // bpermute byte base
  int beg = row_off[n], end = row_off[n + 1];
  float er_h = er[n * 8 + hl];
  float m_run = -INFINITY, s_run = 0.f;
  float acc[8] = {0.f, 0.f, 0.f, 0.f, 0.f, 0.f, 0.f, 0.f};
  for (int c = beg; c < end; c += 8) {
    int cnt = end - c; if (cnt > 8) cnt = 8;
    int s_reg = 0;
    float lg = -INFINITY;
    if (e < cnt) {
      s_reg = src_csr[c + e];
      float xv = el[s_reg * 8 + hl] + er_h;
      lg = (xv >= 0.f) ? xv : 0.2f * xv;
    }
    float m_c = lg;
    m_c = fmaxf(m_c, __shfl_xor(m_c, 8));
    m_c = fmaxf(m_c, __shfl_xor(m_c, 16));
    m_c = fmaxf(m_c, __shfl_xor(m_c, 32));
    float m_new = fmaxf(m_run, m_c);
    float ex = (e < cnt) ? __expf(lg - m_new) : 0.f;
    float sum_c = ex;
    sum_c += __shfl_xor(sum_c, 8);
    sum_c += __shfl_xor(sum_c, 16);
    sum_c += __shfl_xor(sum_c, 32);
    float scale = __expf(m_run - m_new);  // first chunk: exp(-inf)=0
#pragma unroll
    for (int i = 0; i < 8; ++i) acc[i] *= scale;
    s_run = s_run * scale + sum_c;
    m_run = m_new;
    // load phase: batch all row-slices (uniform guards -> SALU skip)
    uint4 fv[8];
#pragma unroll
    for (int e0 = 0; e0 < 8; ++e0) {
      if (e0 < cnt) {
        int s0 = bcast_i(s_reg, e0 * 8);
        fv[e0] = *reinterpret_cast<const uint4*>(fth + (size_t)s0 * F1 + ch);
      }
    }
    // fma phase: broadcast ex per edge, accumulate 8 channels
    int exb = __float_as_int(ex);
#pragma unroll
    for (int e0 = 0; e0 < 8; ++e0) {
      if (e0 < cnt) {
        float ee = __int_as_float(
            __builtin_amdgcn_ds_bpermute(bpbase + e0 * 32, exb));
        float2 f0 = __half22float2(*reinterpret_cast<const __half2*>(&fv[e0].x));
        float2 f1 = __half22float2(*reinterpret_cast<const __half2*>(&fv[e0].y));
        float2 f2 = __half22float2(*reinterpret_cast<const __half2*>(&fv[e0].z));
        float2 f3 = __half22float2(*reinterpret_cast<const __half2*>(&fv[e0].w));
        acc[0] += ee * f0.x; acc[1] += ee * f0.y;
        acc[2] += ee * f1.x; acc[3] += ee * f1.y;
        acc[4] += ee * f2.x; acc[5] += ee * f2.y;
        acc[6] += ee * f3.x; acc[7] += ee * f3.y;
      }
    }
  }
  float inv = (s_run > 0.f) ? (1.f / s_run) : 0.f;
  float o[8];
#pragma unroll
  for (int i = 0; i < 8; ++i) {
    float v = acc[i] * inv + bias[ch + i];
    o[i] = (v > 0.f) ? v : (__expf(v) - 1.f);  // ELU
  }
  float* op = &out[(size_t)n * F1 + ch];
  *reinterpret_cast<float4*>(op) = make_float4(o[0], o[1], o[2], o[3]);
  *reinterpret_cast<float4*>(op + 4) = make_float4(o[4], o[5], o[6], o[7]);
}

// ---- fused GAT layer 2 (H=1, D=64): one wave per node ----
// lane = e*8 + q: edge slot e = lane>>3, channel quad q = lane&7.
// Each lane gathers dwordx4 of ITS edge's row and multiplies by its own ex —
// no broadcasts. Cross-edge reduce once at the end.
template <int NPB>
__global__ __launch_bounds__(NPB * 64) void gat_l2_kernel(
    const int* __restrict__ row_off, const int* __restrict__ src_csr,
    const float* __restrict__ el, const float* __restrict__ er,
    const __half* __restrict__ fth, const float* __restrict__ bias,
    float* __restrict__ out, int N) {
  int t = threadIdx.x;
  int w = t >> 6, lane = t & 63;
  int n = blockIdx.x * NPB + w;
  int e = lane >> 3;
  int ch = (lane & 7) * 8;
  int beg = row_off[n], end = row_off[n + 1];
  float er_n = er[n];
  float m_run = -INFINITY, s_run = 0.f;
  float acc[8] = {0.f, 0.f, 0.f, 0.f, 0.f, 0.f, 0.f, 0.f};
  for (int c = beg; c < end; c += 8) {
    int cnt = end - c; if (cnt > 8) cnt = 8;
    int s_reg = 0;
    float lg = -INFINITY;
    if (e < cnt) {
      s_reg = src_csr[c + e];
      float xv = el[s_reg] + er_n;
      lg = (xv >= 0.f) ? xv : 0.2f * xv;
    }
    float m_c = lg;
    m_c = fmaxf(m_c, __shfl_xor(m_c, 8));
    m_c = fmaxf(m_c, __shfl_xor(m_c, 16));
    m_c = fmaxf(m_c, __shfl_xor(m_c, 32));
    float m_new = fmaxf(m_run, m_c);
    float ex = (e < cnt) ? __expf(lg - m_new) : 0.f;
    float sum_c = ex;
    sum_c += __shfl_xor(sum_c, 8);
    sum_c += __shfl_xor(sum_c, 16);
    sum_c += __shfl_xor(sum_c, 32);
    float scale = __expf(m_run - m_new);
#pragma unroll
    for (int i = 0; i < 8; ++i) acc[i] *= scale;
    s_run = s_run * scale + sum_c;
    m_run = m_new;
    // gather own edge's slice (s_reg=0 fallback row; ex=0 kills contribution)
    uint4 fv = *reinterpret_cast<const uint4*>(fth + (size_t)s_reg * F2 + ch);
    float2 f0 = __half22float2(*reinterpret_cast<const __half2*>(&fv.x));
    float2 f1 = __half22float2(*reinterpret_cast<const __half2*>(&fv.y));
    float2 f2 = __half22float2(*reinterpret_cast<const __half2*>(&fv.z));
    float2 f3 = __half22float2(*reinterpret_cast<const __half2*>(&fv.w));
    acc[0] += ex * f0.x; acc[1] += ex * f0.y;
    acc[2] += ex * f1.x; acc[3] += ex * f1.y;
    acc[4] += ex * f2.x; acc[5] += ex * f2.y;
    acc[6] += ex * f3.x; acc[7] += ex * f3.y;
  }
  // cross-edge-slot reduce
#pragma unroll
  for (int i = 0; i < 8; ++i) {
    acc[i] += __shfl_xor(acc[i], 8);
    acc[i] += __shfl_xor(acc[i], 16);
    acc[i] += __shfl_xor(acc[i], 32);
  }
  float inv = (s_run > 0.f) ? (1.f / s_run) : 0.f;
  if (e == 0) {
    float o[8];
#pragma unroll
    for (int i = 0; i < 8; ++i) o[i] = acc[i] * inv + bias[ch + i];
    float* op = &out[(size_t)n * F2 + ch];
    *reinterpret_cast<float4*>(op) = make_float4(o[0], o[1], o[2], o[3]);
    *reinterpret_cast<float4*>(op + 4) = make_float4(o[4], o[5], o[6], o[7]);
  }
}

extern "C" void kernel_launch(void* const* d_in, const int* in_sizes, int n_in,
                              void* d_out, int out_size, void* d_ws, size_t ws_size,
                              hipStream_t stream) {
  const float* x   = (const float*)d_in[0];
  const int*   src = (const int*)d_in[1];
  const int*   dst = (const int*)d_in[2];
  const float* W1  = (const float*)d_in[3];
  const float* al1 = (const float*)d_in[4];
  const float* ar1 = (const float*)d_in[5];
  const float* b1  = (const float*)d_in[6];
  const float* W2  = (const float*)d_in[7];
  const float* al2 = (const float*)d_in[8];
  const float* ar2 = (const float*)d_in[9];
  const float* b2  = (const float*)d_in[10];
  float* out = (float*)d_out;

  char* ws = (char*)d_ws;
  size_t off = 0;
  auto alloc = [&](size_t bytes) -> void* {
    void* p = ws + off;
    off += (bytes + 255) & ~(size_t)255;
    return p;
  };
  size_t zbeg = off;
  int* counts = (int*)alloc((size_t)N_NODES * 4);
  size_t zend = off;
  float*  h1   = (float*)alloc((size_t)N_NODES * F1 * 4);
  __half* ft1h = (__half*)alloc((size_t)N_NODES * F1 * 2);
  __half* ft2h = (__half*)alloc((size_t)N_NODES * F2 * 2);
  float* el1 = (float*)alloc((size_t)N_NODES * H1 * 4);
  float* er1 = (float*)alloc((size_t)N_NODES * H1 * 4);
  float* el2 = (float*)alloc((size_t)N_NODES * 4);
  float* er2 = (float*)alloc((size_t)N_NODES * 4);
  int* row_off = (int*)alloc((size_t)(N_NODES + 1) * 4);
  int* cursor  = (int*)alloc((size_t)N_NODES * 4);
  int* src_csr = (int*)alloc((size_t)N_EDGES * 4);
  (void)ws_size; (void)in_sizes; (void)n_in; (void)out_size;

  hipMemsetAsync(ws + zbeg, 0, zend - zbeg, stream);

  dim3 b256(256);
  int egrid = (N_EDGES + 255) / 256;

  // CSR build
  hist_kernel<<<egrid, b256, 0, stream>>>(dst, counts, N_EDGES);
  scan_kernel<<<1, 1024, 0, stream>>>(counts, row_off, cursor, N_NODES);
  scatter_kernel<<<egrid, b256, 0, stream>>>(src, dst, cursor, src_csr, N_EDGES);

  // ---- layer 1 ----
  gemm_epi<<<dim3(F1 / 64, (N_NODES + 63) / 64), b256, 0, stream>>>(
      x, W1, ft1h, al1, ar1, el1, er1, N_NODES, F1, IN_SIZE, H1);
  gat_l1_kernel<4><<<N_NODES / 4, 256, 0, stream>>>(
      row_off, src_csr, el1, er1, ft1h, b1, h1, N_NODES);

  // ---- layer 2 ----
  gemm_epi<<<dim3(F2 / 64, (N_NODES + 63) / 64), b256, 0, stream>>>(
      h1, W2, ft2h, al2, ar2, el2, er2, N_NODES, F2, F1, H2);
  gat_l2_kernel<4><<<N_NODES / 4, 256, 0, stream>>>(
      row_off, src_csr, el2, er2, ft2h, b2, out, N_NODES);
}

// Round 8
// 192.065 us; speedup vs baseline: 1.4518x; 1.1267x over previous
//
#include <hip/hip_runtime.h>
#include <hip/hip_bf16.h>
#include <hip/hip_fp16.h>
#include <math.h>

#define N_NODES 10000
#define N_EDGES 320000
#define IN_SIZE 256
#define H1 8
#define D1 64
#define F1 512
#define H2 1
#define D2 64
#define F2 64

using f16x8 = __attribute__((ext_vector_type(8))) _Float16;
using f32x4 = __attribute__((ext_vector_type(4))) float;

// ---- conversions ----
__global__ void f32_to_f16_vec(const float* __restrict__ in, __half* __restrict__ out, int n4) {
  int i = blockIdx.x * blockDim.x + threadIdx.x;
  if (i < n4) {
    float4 v = reinterpret_cast<const float4*>(in)[i];
    __half2 a = __floats2half2_rn(v.x, v.y);
    __half2 b = __floats2half2_rn(v.z, v.w);
    reinterpret_cast<__half2*>(out)[i * 2 + 0] = a;
    reinterpret_cast<__half2*>(out)[i * 2 + 1] = b;
  }
}

// W [K][N] f32 -> WT [N][K] f16
__global__ void transpose_to_f16(const float* __restrict__ in, __half* __restrict__ out,
                                 int K, int N) {
  int i = blockIdx.x * blockDim.x + threadIdx.x;
  if (i < K * N) {
    int k = i / N, n = i % N;
    out[(size_t)n * K + k] = __float2half(in[i]);
  }
}

// ---- MFMA f16 GEMM (64x64 tile / block, 4 waves, no LDS) + epilogue ----
// A [M][K] f16 row-major; BT [N][K] f16 (pre-transposed). Writes Ch f16 and
// el/er = C . al / C . ar per row (per 64-wide head = col block).
// Permutation-safe fragment mapping: same (lane>>4, j)->k for A and B.
template <int KSTEPS>
__global__ __launch_bounds__(256) void gemm_mfma(
    const __half* __restrict__ A, const __half* __restrict__ BT,
    __half* __restrict__ Ch, const float* __restrict__ al,
    const float* __restrict__ ar, float* __restrict__ el,
    float* __restrict__ er, int M, int Ncols, int H) {
  constexpr int K = KSTEPS * 32;
  int tid = threadIdx.x;
  int w = tid >> 6, lane = tid & 63;
  int rowBase = blockIdx.y * 64 + w * 16;
  int colBase = blockIdx.x * 64;
  int r16 = lane & 15;
  int ko = lane >> 4;
  int arow = rowBase + r16;
  if (arow >= M) arow = M - 1;
  const f16x8* Ap = reinterpret_cast<const f16x8*>(A + (size_t)arow * K + ko * 8);
  const __half* Bbase = BT + (size_t)colBase * K + ko * 8;
  f32x4 acc[4] = {};
#pragma unroll
  for (int kk = 0; kk < KSTEPS; ++kk) {
    f16x8 af = Ap[kk * 4];
#pragma unroll
    for (int c = 0; c < 4; ++c) {
      f16x8 bf = *reinterpret_cast<const f16x8*>(
          Bbase + (size_t)(c * 16 + r16) * K + kk * 32);
      acc[c] = __builtin_amdgcn_mfma_f32_16x16x32_f16(af, bf, acc[c], 0, 0, 0);
    }
  }
  int h = colBase >> 6;
  float alv[4], arv[4];
#pragma unroll
  for (int c = 0; c < 4; ++c) {
    alv[c] = al[colBase + c * 16 + r16];
    arv[c] = ar[colBase + c * 16 + r16];
  }
#pragma unroll
  for (int r = 0; r < 4; ++r) {
    int row = rowBase + (lane >> 4) * 4 + r;
    bool ok = row < M;
    float pl = 0.f, pr = 0.f;
#pragma unroll
    for (int c = 0; c < 4; ++c) {
      float v = acc[c][r];
      if (ok) Ch[(size_t)row * Ncols + colBase + c * 16 + r16] = __float2half(v);
      pl += v * alv[c];
      pr += v * arv[c];
    }
#pragma unroll
    for (int o = 8; o > 0; o >>= 1) {
      pl += __shfl_xor(pl, o);
      pr += __shfl_xor(pr, o);
    }
    if (r16 == 0 && ok) {
      el[(size_t)row * H + h] = pl;
      er[(size_t)row * H + h] = pr;
    }
  }
}

// ---- CSR build ----
__global__ void hist_kernel(const int* __restrict__ dst, int* __restrict__ counts, int E) {
  int e = blockIdx.x * blockDim.x + threadIdx.x;
  if (e < E) atomicAdd(&counts[dst[e]], 1);
}

__global__ __launch_bounds__(1024) void scan_kernel(const int* __restrict__ counts,
                                                    int* __restrict__ row_off,
                                                    int* __restrict__ cursor, int N) {
  __shared__ int part[1024];
  int tid = threadIdx.x;
  int T = blockDim.x;
  int chunk = (N + T - 1) / T;
  int beg = tid * chunk;
  int end = min(beg + chunk, N);
  int s = 0;
  for (int i = beg; i < end; ++i) s += counts[i];
  part[tid] = s;
  __syncthreads();
  for (int off = 1; off < T; off <<= 1) {
    int v = (tid >= off) ? part[tid - off] : 0;
    __syncthreads();
    part[tid] += v;
    __syncthreads();
  }
  int run = (tid > 0) ? part[tid - 1] : 0;
  for (int i = beg; i < end; ++i) {
    row_off[i] = run;
    cursor[i] = run;
    run += counts[i];
  }
  if (tid == T - 1) row_off[N] = run;
}

__global__ void scatter_kernel(const int* __restrict__ src, const int* __restrict__ dst,
                               int* __restrict__ cursor, int* __restrict__ src_csr, int E) {
  int e = blockIdx.x * blockDim.x + threadIdx.x;
  if (e < E) {
    int p = atomicAdd(&cursor[dst[e]], 1);
    src_csr[p] = src[e];
  }
}

__device__ __forceinline__ int bcast_i(int v, int l) {
  return __builtin_amdgcn_readlane(v, l);
}

// ---- fused GAT layer 1: SPLIT waves per node, all 8 heads per wave ----
// logit phase: lane = e*8+h; agg phase: lane = (head=lane&7, quad=lane>>3).
// m_run/s_run are PER-HEAD (head = lane&7): the xor-8/16/32 reduce covers
// edge slots for a fixed head. Merge must therefore be per-head: lms[w][8][2]
// written by lanes 0..7 (one per head).
template <int NPB, int SPLIT>
__global__ __launch_bounds__(NPB * SPLIT * 64) void gat_l1_kernel(
    const int* __restrict__ row_off, const int* __restrict__ src_csr,
    const float* __restrict__ el, const float* __restrict__ er,
    const __half* __restrict__ fth, const float* __restrict__ bias,
    __half* __restrict__ out, int N) {
  constexpr int NW = NPB * SPLIT;
  __shared__ float lacc[NW][64][8];
  __shared__ float lms[NW][8][2];
  int t = threadIdx.x;
  int w = t >> 6, lane = t & 63;
  int ni = w / SPLIT, sw = w % SPLIT;
  int n = blockIdx.x * NPB + ni;
  int e = lane >> 3;
  int hl = lane & 7;
  int ch = (lane & 7) * 64 + (lane >> 3) * 8;
  int bpbase = (lane & 7) * 4;
  int beg = row_off[n], end = row_off[n + 1];
  int deg = end - beg;
  int per = (deg + SPLIT - 1) / SPLIT;
  int b2 = beg + sw * per; if (b2 > end) b2 = end;
  int e2 = b2 + per;       if (e2 > end) e2 = end;
  float er_h = er[n * 8 + hl];
  float m_run = -INFINITY, s_run = 0.f;
  float acc[8] = {0.f, 0.f, 0.f, 0.f, 0.f, 0.f, 0.f, 0.f};
  for (int c = b2; c < e2; c += 8) {
    int cnt = e2 - c; if (cnt > 8) cnt = 8;
    int s_reg = 0;
    float lg = -INFINITY;
    if (e < cnt) {
      s_reg = src_csr[c + e];
      float xv = el[s_reg * 8 + hl] + er_h;
      lg = (xv >= 0.f) ? xv : 0.2f * xv;
    }
    float m_c = lg;
    m_c = fmaxf(m_c, __shfl_xor(m_c, 8));
    m_c = fmaxf(m_c, __shfl_xor(m_c, 16));
    m_c = fmaxf(m_c, __shfl_xor(m_c, 32));
    float m_new = fmaxf(m_run, m_c);
    float ex = (e < cnt) ? __expf(lg - m_new) : 0.f;
    float sum_c = ex;
    sum_c += __shfl_xor(sum_c, 8);
    sum_c += __shfl_xor(sum_c, 16);
    sum_c += __shfl_xor(sum_c, 32);
    float scale = __expf(m_run - m_new);  // first chunk: exp(-inf)=0
#pragma unroll
    for (int i = 0; i < 8; ++i) acc[i] *= scale;
    s_run = s_run * scale + sum_c;
    m_run = m_new;
    uint4 fv[8];
#pragma unroll
    for (int e0 = 0; e0 < 8; ++e0) {
      if (e0 < cnt) {
        int s0 = bcast_i(s_reg, e0 * 8);
        fv[e0] = *reinterpret_cast<const uint4*>(fth + (size_t)s0 * F1 + ch);
      }
    }
    int exb = __float_as_int(ex);
#pragma unroll
    for (int e0 = 0; e0 < 8; ++e0) {
      if (e0 < cnt) {
        float ee = __int_as_float(
            __builtin_amdgcn_ds_bpermute(bpbase + e0 * 32, exb));
        float2 f0 = __half22float2(*reinterpret_cast<const __half2*>(&fv[e0].x));
        float2 f1 = __half22float2(*reinterpret_cast<const __half2*>(&fv[e0].y));
        float2 f2 = __half22float2(*reinterpret_cast<const __half2*>(&fv[e0].z));
        float2 f3 = __half22float2(*reinterpret_cast<const __half2*>(&fv[e0].w));
        acc[0] += ee * f0.x; acc[1] += ee * f0.y;
        acc[2] += ee * f1.x; acc[3] += ee * f1.y;
        acc[4] += ee * f2.x; acc[5] += ee * f2.y;
        acc[6] += ee * f3.x; acc[7] += ee * f3.y;
      }
    }
  }
  // merge SPLIT partials (per-head m/s state!)
#pragma unroll
  for (int i = 0; i < 8; ++i) lacc[w][lane][i] = acc[i];
  if (lane < 8) { lms[w][lane][0] = m_run; lms[w][lane][1] = s_run; }
  __syncthreads();
  if (sw != 0) return;
  float m_star = m_run;
#pragma unroll
  for (int k = 1; k < SPLIT; ++k) m_star = fmaxf(m_star, lms[w + k][hl][0]);
  float sc0 = (m_run == -INFINITY) ? 0.f : __expf(m_run - m_star);
#pragma unroll
  for (int i = 0; i < 8; ++i) acc[i] *= sc0;
  s_run *= sc0;
#pragma unroll
  for (int k = 1; k < SPLIT; ++k) {
    float mk = lms[w + k][hl][0];
    float sc = (mk == -INFINITY) ? 0.f : __expf(mk - m_star);
    s_run += lms[w + k][hl][1] * sc;
#pragma unroll
    for (int i = 0; i < 8; ++i) acc[i] += lacc[w + k][lane][i] * sc;
  }
  float inv = (s_run > 0.f) ? (1.f / s_run) : 0.f;
  uint4 pack;
  __half2* ph = reinterpret_cast<__half2*>(&pack);
#pragma unroll
  for (int i = 0; i < 4; ++i) {
    float v0 = acc[2 * i + 0] * inv + bias[ch + 2 * i + 0];
    float v1 = acc[2 * i + 1] * inv + bias[ch + 2 * i + 1];
    v0 = (v0 > 0.f) ? v0 : (__expf(v0) - 1.f);
    v1 = (v1 > 0.f) ? v1 : (__expf(v1) - 1.f);
    ph[i] = __floats2half2_rn(v0, v1);
  }
  *reinterpret_cast<uint4*>(out + (size_t)n * F1 + ch) = pack;
}

// ---- fused GAT layer 2 (H=1): SPLIT waves per node ----
// lane = e*8 + q; m_run/s_run are wave-uniform (H=1), lane-0 merge is safe.
template <int NPB, int SPLIT>
__global__ __launch_bounds__(NPB * SPLIT * 64) void gat_l2_kernel(
    const int* __restrict__ row_off, const int* __restrict__ src_csr,
    const float* __restrict__ el, const float* __restrict__ er,
    const __half* __restrict__ fth, const float* __restrict__ bias,
    float* __restrict__ out, int N) {
  constexpr int NW = NPB * SPLIT;
  __shared__ float lacc[NW][8][8];
  __shared__ float lms[NW][2];
  int t = threadIdx.x;
  int w = t >> 6, lane = t & 63;
  int ni = w / SPLIT, sw = w % SPLIT;
  int n = blockIdx.x * NPB + ni;
  int e = lane >> 3;
  int q = lane & 7;
  int ch = q * 8;
  int beg = row_off[n], end = row_off[n + 1];
  int deg = end - beg;
  int per = (deg + SPLIT - 1) / SPLIT;
  int b2 = beg + sw * per; if (b2 > end) b2 = end;
  int e2 = b2 + per;       if (e2 > end) e2 = end;
  float er_n = er[n];
  float m_run = -INFINITY, s_run = 0.f;
  float acc[8] = {0.f, 0.f, 0.f, 0.f, 0.f, 0.f, 0.f, 0.f};
  for (int c = b2; c < e2; c += 8) {
    int cnt = e2 - c; if (cnt > 8) cnt = 8;
    int s_reg = 0;
    float lg = -INFINITY;
    if (e < cnt) {
      s_reg = src_csr[c + e];
      float xv = el[s_reg] + er_n;
      lg = (xv >= 0.f) ? xv : 0.2f * xv;
    }
    float m_c = lg;
    m_c = fmaxf(m_c, __shfl_xor(m_c, 8));
    m_c = fmaxf(m_c, __shfl_xor(m_c, 16));
    m_c = fmaxf(m_c, __shfl_xor(m_c, 32));
    float m_new = fmaxf(m_run, m_c);
    float ex = (e < cnt) ? __expf(lg - m_new) : 0.f;
    float sum_c = ex;
    sum_c += __shfl_xor(sum_c, 8);
    sum_c += __shfl_xor(sum_c, 16);
    sum_c += __shfl_xor(sum_c, 32);
    float scale = __expf(m_run - m_new);
#pragma unroll
    for (int i = 0; i < 8; ++i) acc[i] *= scale;
    s_run = s_run * scale + sum_c;
    m_run = m_new;
    uint4 fv = *reinterpret_cast<const uint4*>(fth + (size_t)s_reg * F2 + ch);
    float2 f0 = __half22float2(*reinterpret_cast<const __half2*>(&fv.x));
    float2 f1 = __half22float2(*reinterpret_cast<const __half2*>(&fv.y));
    float2 f2 = __half22float2(*reinterpret_cast<const __half2*>(&fv.z));
    float2 f3 = __half22float2(*reinterpret_cast<const __half2*>(&fv.w));
    acc[0] += ex * f0.x; acc[1] += ex * f0.y;
    acc[2] += ex * f1.x; acc[3] += ex * f1.y;
    acc[4] += ex * f2.x; acc[5] += ex * f2.y;
    acc[6] += ex * f3.x; acc[7] += ex * f3.y;
  }
#pragma unroll
  for (int i = 0; i < 8; ++i) {
    acc[i] += __shfl_xor(acc[i], 8);
    acc[i] += __shfl_xor(acc[i], 16);
    acc[i] += __shfl_xor(acc[i], 32);
  }
  if (e == 0) {
#pragma unroll
    for (int i = 0; i < 8; ++i) lacc[w][q][i] = acc[i];
  }
  if (lane == 0) { lms[w][0] = m_run; lms[w][1] = s_run; }
  __syncthreads();
  if (sw != 0 || e != 0) return;
  float m_star = m_run;
#pragma unroll
  for (int k = 1; k < SPLIT; ++k) m_star = fmaxf(m_star, lms[w + k][0]);
  float sc0 = (m_run == -INFINITY) ? 0.f : __expf(m_run - m_star);
#pragma unroll
  for (int i = 0; i < 8; ++i) acc[i] *= sc0;
  s_run *= sc0;
#pragma unroll
  for (int k = 1; k < SPLIT; ++k) {
    float mk = lms[w + k][0];
    float sc = (mk == -INFINITY) ? 0.f : __expf(mk - m_star);
    s_run += lms[w + k][1] * sc;
#pragma unroll
    for (int i = 0; i < 8; ++i) acc[i] += lacc[w + k][q][i] * sc;
  }
  float inv = (s_run > 0.f) ? (1.f / s_run) : 0.f;
  float o[8];
#pragma unroll
  for (int i = 0; i < 8; ++i) o[i] = acc[i] * inv + bias[ch + i];
  float* op = &out[(size_t)n * F2 + ch];
  *reinterpret_cast<float4*>(op) = make_float4(o[0], o[1], o[2], o[3]);
  *reinterpret_cast<float4*>(op + 4) = make_float4(o[4], o[5], o[6], o[7]);
}

extern "C" void kernel_launch(void* const* d_in, const int* in_sizes, int n_in,
                              void* d_out, int out_size, void* d_ws, size_t ws_size,
                              hipStream_t stream) {
  const float* x   = (const float*)d_in[0];
  const int*   src = (const int*)d_in[1];
  const int*   dst = (const int*)d_in[2];
  const float* W1  = (const float*)d_in[3];
  const float* al1 = (const float*)d_in[4];
  const float* ar1 = (const float*)d_in[5];
  const float* b1  = (const float*)d_in[6];
  const float* W2  = (const float*)d_in[7];
  const float* al2 = (const float*)d_in[8];
  const float* ar2 = (const float*)d_in[9];
  const float* b2  = (const float*)d_in[10];
  float* out = (float*)d_out;

  char* ws = (char*)d_ws;
  size_t off = 0;
  auto alloc = [&](size_t bytes) -> void* {
    void* p = ws + off;
    off += (bytes + 255) & ~(size_t)255;
    return p;
  };
  size_t zbeg = off;
  int* counts = (int*)alloc((size_t)N_NODES * 4);
  size_t zend = off;
  __half* xh   = (__half*)alloc((size_t)N_NODES * IN_SIZE * 2);
  __half* W1T  = (__half*)alloc((size_t)IN_SIZE * F1 * 2);
  __half* W2T  = (__half*)alloc((size_t)F1 * F2 * 2);
  __half* ft1h = (__half*)alloc((size_t)N_NODES * F1 * 2);
  __half* h1h  = (__half*)alloc((size_t)N_NODES * F1 * 2);
  __half* ft2h = (__half*)alloc((size_t)N_NODES * F2 * 2);
  float* el1 = (float*)alloc((size_t)N_NODES * H1 * 4);
  float* er1 = (float*)alloc((size_t)N_NODES * H1 * 4);
  float* el2 = (float*)alloc((size_t)N_NODES * 4);
  float* er2 = (float*)alloc((size_t)N_NODES * 4);
  int* row_off = (int*)alloc((size_t)(N_NODES + 1) * 4);
  int* cursor  = (int*)alloc((size_t)N_NODES * 4);
  int* src_csr = (int*)alloc((size_t)N_EDGES * 4);
  (void)ws_size; (void)in_sizes; (void)n_in; (void)out_size;

  hipMemsetAsync(ws + zbeg, 0, zend - zbeg, stream);

  dim3 b256(256);
  int egrid = (N_EDGES + 255) / 256;

  // CSR build
  hist_kernel<<<egrid, b256, 0, stream>>>(dst, counts, N_EDGES);
  scan_kernel<<<1, 1024, 0, stream>>>(counts, row_off, cursor, N_NODES);
  scatter_kernel<<<egrid, b256, 0, stream>>>(src, dst, cursor, src_csr, N_EDGES);

  // input conversions
  f32_to_f16_vec<<<(N_NODES * IN_SIZE / 4 + 255) / 256, b256, 0, stream>>>(
      x, xh, N_NODES * IN_SIZE / 4);
  transpose_to_f16<<<(IN_SIZE * F1 + 255) / 256, b256, 0, stream>>>(W1, W1T, IN_SIZE, F1);
  transpose_to_f16<<<(F1 * F2 + 255) / 256, b256, 0, stream>>>(W2, W2T, F1, F2);

  // ---- layer 1 ----
  gemm_mfma<IN_SIZE / 32><<<dim3(F1 / 64, (N_NODES + 63) / 64), b256, 0, stream>>>(
      xh, W1T, ft1h, al1, ar1, el1, er1, N_NODES, F1, H1);
  gat_l1_kernel<4, 2><<<N_NODES / 4, 512, 0, stream>>>(
      row_off, src_csr, el1, er1, ft1h, b1, h1h, N_NODES);

  // ---- layer 2 ----
  gemm_mfma<F1 / 32><<<dim3(F2 / 64, (N_NODES + 63) / 64), b256, 0, stream>>>(
      h1h, W2T, ft2h, al2, ar2, el2, er2, N_NODES, F2, H2);
  gat_l2_kernel<4, 2><<<N_NODES / 4, 512, 0, stream>>>(
      row_off, src_csr, el2, er2, ft2h, b2, out, N_NODES);
}